// Round 2
// baseline (24157.666 us; speedup 1.0000x reference)
//
#include <hip/hip_runtime.h>
#include <hip/hip_fp16.h>

typedef _Float16 f16;
typedef _Float16 f16x8 __attribute__((ext_vector_type(8)));
typedef _Float16 f16x4 __attribute__((ext_vector_type(4)));
typedef float    f32x4 __attribute__((ext_vector_type(4)));

#define LN_EPS 1e-6f
#define AGT __HIP_MEMORY_SCOPE_AGENT
// B=16 S=512 H=1024 V=32000 L=2

// ---------------------------------------------------------------------------
// embed fp32 -> f16 (for logits GEMM B operand)
__global__ void k_cvt(const float* __restrict__ in, f16* __restrict__ out, int n4) {
    int i = blockIdx.x * 256 + threadIdx.x;
    int st = gridDim.x * 256;
    for (; i < n4; i += st) {
        float4 v = ((const float4*)in)[i];
        f16x4 o = { (f16)v.x, (f16)v.y, (f16)v.z, (f16)v.w };
        ((f16x4*)out)[i] = o;
    }
}

// ---------------------------------------------------------------------------
// per-(t,b) LayerNorm stats of the embedding rows (layer-0 input)
__global__ void k_xstat(const int* __restrict__ x, const float* __restrict__ embed,
                        float2* __restrict__ xstat) {
    int r = blockIdx.x * 4 + (threadIdx.x >> 6);   // r = t*16 + b, 8192 rows
    int lane = threadIdx.x & 63;
    int t = r >> 4, b = r & 15;
    int tok = x[b * 512 + t];
    const float4* p = (const float4*)(embed + (size_t)tok * 1024);
    float sum = 0.f, sq = 0.f;
    #pragma unroll
    for (int j = 0; j < 4; ++j) {
        float4 v = p[lane * 4 + j];
        sum += v.x + v.y + v.z + v.w;
        sq  += v.x*v.x + v.y*v.y + v.z*v.z + v.w*v.w;
    }
    #pragma unroll
    for (int m = 1; m < 64; m <<= 1) {
        sum += __shfl_xor(sum, m);
        sq  += __shfl_xor(sq,  m);
    }
    if (lane == 0) {
        float mu  = sum * (1.f / 1024.f);
        float var = sq  * (1.f / 1024.f) - mu * mu;
        xstat[r] = make_float2(mu, rsqrtf(var + LN_EPS));
    }
}

// ---------------------------------------------------------------------------
// xn0[r][c] = f16( (embed[x]-mu)*rsig*g0 + b0 ), r = t*16+b, 8192 rows
__global__ void k_xnorm(const int* __restrict__ x, const float* __restrict__ embed,
                        const float2* __restrict__ xstat,
                        const float* __restrict__ gamma, const float* __restrict__ beta,
                        f16* __restrict__ xn0) {
    int r = blockIdx.x;
    int t = r >> 4, b = r & 15;
    int tok = x[b * 512 + t];
    int c = threadIdx.x * 4;
    float4 e = *(const float4*)(embed + (size_t)tok * 1024 + c);
    float4 g = *(const float4*)(gamma + c);
    float4 q = *(const float4*)(beta + c);
    float2 st = xstat[r];
    f16x4 o;
    o[0] = (f16)((e.x - st.x) * st.y * g.x + q.x);
    o[1] = (f16)((e.y - st.x) * st.y * g.y + q.y);
    o[2] = (f16)((e.z - st.x) * st.y * g.z + q.z);
    o[3] = (f16)((e.w - st.x) * st.y * g.w + q.w);
    *(f16x4*)(xn0 + (size_t)r * 1024 + c) = o;
}

// ---------------------------------------------------------------------------
// transpose+cvt W halves to f16 [4096][1024]; mat2 (Wx of layer1) folds gamma1.
__global__ void k_wprep(const float* __restrict__ W, const float* __restrict__ gamma,
                        f16* __restrict__ WxT0, f16* __restrict__ WhT0,
                        f16* __restrict__ WxT1, f16* __restrict__ WhT1) {
    __shared__ float tile[64][65];
    int mat = blockIdx.x >> 10, t = blockIdx.x & 1023;
    int ct = t >> 4, kt = t & 15;
    int layer = mat >> 1, half = mat & 1;
    const float* src = W + (size_t)layer * 2048 * 4096 + (size_t)half * 1024 * 4096;
    int kl = threadIdx.x >> 2, cseg = (threadIdx.x & 3) * 16;
    float g = (mat == 2) ? gamma[1024 + kt * 64 + kl] : 1.f;
    const float* srow = src + (size_t)(kt * 64 + kl) * 4096 + ct * 64 + cseg;
    #pragma unroll
    for (int j = 0; j < 4; ++j) {
        float4 v = *(const float4*)(srow + j * 4);
        tile[kl][cseg + j*4 + 0] = v.x * g;
        tile[kl][cseg + j*4 + 1] = v.y * g;
        tile[kl][cseg + j*4 + 2] = v.z * g;
        tile[kl][cseg + j*4 + 3] = v.w * g;
    }
    __syncthreads();
    f16* dst = (mat == 0) ? WxT0 : (mat == 1) ? WhT0 : (mat == 2) ? WxT1 : WhT1;
    int cl = threadIdx.x >> 2, kseg = (threadIdx.x & 3) * 16;
    f16x8 o0, o1;
    #pragma unroll
    for (int j = 0; j < 8; ++j) o0[j] = (f16)tile[kseg + j][cl];
    #pragma unroll
    for (int j = 0; j < 8; ++j) o1[j] = (f16)tile[kseg + 8 + j][cl];
    f16* drow = dst + (size_t)(ct * 64 + cl) * 1024 + kt * 64 + kseg;
    *(f16x8*)drow = o0;
    *(f16x8*)(drow + 8) = o1;
}

// ---------------------------------------------------------------------------
// G1[c] = sum_k g1[k]*Wx1[k][c];  Bv1[c] = sum_k b1[k]*Wx1[k][c]
__global__ void k_gb(const float* __restrict__ W, const float* __restrict__ gamma,
                     const float* __restrict__ beta,
                     float* __restrict__ G1, float* __restrict__ Bv1) {
    int c = blockIdx.x * 256 + threadIdx.x;
    const float* src = W + (size_t)1 * 2048 * 4096;   // layer-1 Wx half
    float G = 0.f, Bv = 0.f;
    for (int k = 0; k < 1024; ++k) {
        float w = src[(size_t)k * 4096 + c];
        G  += gamma[1024 + k] * w;
        Bv += beta[1024 + k] * w;
    }
    G1[c] = G;
    Bv1[c] = Bv;
}

// ---------------------------------------------------------------------------
// zx0 = xn0(f16 [8192][1024]) @ WxT0(f16 [4096][1024])^T -> f16 [8192][4096]
__global__ void __launch_bounds__(256)
k_zx(const f16* __restrict__ A, const f16* __restrict__ Bm, f16* __restrict__ out) {
    __shared__ f16 Asm[128 * 64];
    __shared__ f16 Bsm[128 * 64];
    const int nwg = gridDim.x;                       // 2048
    int swz = (blockIdx.x % 8) * (nwg / 8) + blockIdx.x / 8;
    const int tm = swz / 32;
    const int tn = swz % 32;
    const int tid = threadIdx.x;
    const int lane = tid & 63;
    const int wv = tid >> 6;
    const int wm = wv >> 1, wn = wv & 1;

    f32x4 acc[4][4] = {};
    const f16* Ab = A  + (size_t)(tm * 128) * 1024;
    const f16* Bb = Bm + (size_t)(tn * 128) * 1024;

    for (int kt = 0; kt < 16; ++kt) {
        uint4 ra[4], rb[4];
        #pragma unroll
        for (int j = 0; j < 4; ++j) {
            int c = tid + j * 256;
            int row = c >> 3, slot = c & 7;
            ra[j] = *(const uint4*)(Ab + (size_t)row * 1024 + kt * 64 + slot * 8);
            rb[j] = *(const uint4*)(Bb + (size_t)row * 1024 + kt * 64 + slot * 8);
        }
        __syncthreads();
        #pragma unroll
        for (int j = 0; j < 4; ++j) {
            int c = tid + j * 256;
            int row = c >> 3, slot = c & 7;
            int off = row * 128 + ((slot ^ (row & 7)) << 4);
            *(uint4*)((char*)Asm + off) = ra[j];
            *(uint4*)((char*)Bsm + off) = rb[j];
        }
        __syncthreads();
        #pragma unroll
        for (int ks = 0; ks < 2; ++ks) {
            f16x8 af[4], bf[4];
            #pragma unroll
            for (int mi = 0; mi < 4; ++mi) {
                int row = wm * 64 + mi * 16 + (lane & 15);
                int slot = ks * 4 + (lane >> 4);
                af[mi] = *(const f16x8*)((const char*)Asm + row * 128 + ((slot ^ (row & 7)) << 4));
            }
            #pragma unroll
            for (int ni = 0; ni < 4; ++ni) {
                int row = wn * 64 + ni * 16 + (lane & 15);
                int slot = ks * 4 + (lane >> 4);
                bf[ni] = *(const f16x8*)((const char*)Bsm + row * 128 + ((slot ^ (row & 7)) << 4));
            }
            #pragma unroll
            for (int mi = 0; mi < 4; ++mi)
                #pragma unroll
                for (int ni = 0; ni < 4; ++ni)
                    acc[mi][ni] = __builtin_amdgcn_mfma_f32_16x16x32_f16(af[mi], bf[ni], acc[mi][ni], 0, 0, 0);
        }
    }
    #pragma unroll
    for (int mi = 0; mi < 4; ++mi) {
        int mrow = tm * 128 + wm * 64 + mi * 16 + (lane >> 4) * 4;
        #pragma unroll
        for (int ni = 0; ni < 4; ++ni) {
            int col = tn * 128 + wn * 64 + ni * 16 + (lane & 15);
            #pragma unroll
            for (int r = 0; r < 4; ++r)
                out[(size_t)(mrow + r) * 4096 + col] = (f16)acc[mi][ni][r];
        }
    }
}

// ---------------------------------------------------------------------------
// Persistent recurrence: 256 blocks, layer = blk&1, g = blk>>1 (8 units each).
// Custom flag-array barriers per layer group + cross-group progress words.
// LDS: W [1-2][32][1024] f16 swizzled; (L0) xtok 32KB; zred 8KB @131072; stats @139264.
#define GRP 128
__global__ void __launch_bounds__(256, 1)
k_recur(const int* __restrict__ x, const float* __restrict__ embed,
        const float* __restrict__ bias,
        const f16* __restrict__ zx0,
        const f16* __restrict__ WhT0, const f16* __restrict__ WxT1,
        const f16* __restrict__ WhT1,
        const float* __restrict__ G1v, const float* __restrict__ Bv1,
        f16* __restrict__ h0buf, f16* __restrict__ h1buf,   // [2][16][1024]
        f16* __restrict__ inp1,                             // [4][16][1024]
        f16* __restrict__ hseq,                             // [8192][1024]
        unsigned* flags,
        float* __restrict__ cout)
{
    extern __shared__ char smem[];
    float* zred  = (float*)(smem + 131072);
    float* stats = (float*)(smem + 131072 + 8192);

    const int tid = threadIdx.x;
    const int lane = tid & 63;
    const int wv = tid >> 6;
    const int blk = blockIdx.x;
    const int layer = blk & 1;
    const int g = blk >> 1;
    const int base = g * 8;

    unsigned* arrive    = flags + layer * (GRP * 16);
    unsigned* progSelf  = flags + 2 * GRP * 16 + layer * 32;
    unsigned* progOther = flags + 2 * GRP * 16 + (1 - layer) * 32;

    // ---- W preload (coalesced from pre-transposed f16), swizzled LDS
    if (layer == 0) {
        for (int t = tid; t < 4096; t += 256) {
            int lc = t >> 7, ch = t & 127;
            int c = (lc >> 3) * 1024 + base + (lc & 7);
            f16x8 v = *(const f16x8*)(WhT0 + (size_t)c * 1024 + ch * 8);
            int off = (lc * 2048 + ch * 16) ^ ((lc & 7) << 4);
            *(f16x8*)(smem + off) = v;
        }
        int4* xl = (int4*)(smem + 65536);
        for (int t = tid; t < 2048; t += 256) xl[t] = ((const int4*)x)[t];
    } else {
        for (int t = tid; t < 8192; t += 256) {
            int mat = t >> 12, r = t & 4095;
            int lc = r >> 7, ch = r & 127;
            int c = (lc >> 3) * 1024 + base + (lc & 7);
            const f16* src = mat ? WhT1 : WxT1;
            f16x8 v = *(const f16x8*)(src + (size_t)c * 1024 + ch * 8);
            int off = mat * 65536 + ((lc * 2048 + ch * 16) ^ ((lc & 7) << 4));
            *(f16x8*)(smem + off) = v;
        }
    }

    // gate-thread constants
    const int grow = tid >> 3, gu = tid & 7;
    const int gcol = base + gu;
    float bz[4], Gg[4], Cg[4];
    if (tid < 128) {
        #pragma unroll
        for (int q = 0; q < 4; ++q) {
            int cg = q * 1024 + gcol;
            bz[q] = bias[layer * 4096 + cg];
            if (layer) { Gg[q] = G1v[cg]; Cg[q] = Bv1[cg] + bz[q]; }
        }
    }
    float creg = 0.f;
    const int arow = lane & 15;
    const int koff = (lane >> 4) * 8;
    const int lcA = lane & 15;

    __syncthreads();

    if (layer == 0) {
        const int* xtok = (const int*)(smem + 65536);
        for (int tick = 0; tick < 512; ++tick) {
            // prefetch (immutable data): zx0 row slice + embed gather
            float zx[4]; float xe = 0.f;
            if (tid < 128) {
                const f16* zr = zx0 + (size_t)(tick * 16 + grow) * 4096;
                #pragma unroll
                for (int q = 0; q < 4; ++q) zx[q] = (float)zr[q * 1024 + gcol];
                int tok = xtok[grow * 512 + tick];
                xe = embed[(size_t)tok * 1024 + gcol];
            }
            // slot-reuse guard: L1 must be done reading inp1[step tick-4]
            if (tick >= 4) {
                unsigned tgt = (unsigned)(tick - 3);
                while (__hip_atomic_load(progOther, __ATOMIC_RELAXED, AGT) < tgt) {}
            }
            // h-half GEMM: h0[tick-1] @ Wh0
            const f16* hrow = h0buf + ((tick + 1) & 1) * 16384 + arow * 1024;
            f32x4 acc0 = {0.f,0.f,0.f,0.f}, acc1 = {0.f,0.f,0.f,0.f};
            #pragma unroll
            for (int ks = 0; ks < 8; ++ks) {
                int k0 = wv * 256 + ks * 32 + koff;
                f16x8 ha = *(const f16x8*)(hrow + k0);
                int swz0 = (lcA * 2048 + k0 * 2) ^ ((lcA & 7) << 4);
                acc0 = __builtin_amdgcn_mfma_f32_16x16x32_f16(ha, *(const f16x8*)(smem + swz0), acc0, 0, 0, 0);
                int lc1 = 16 + lcA;
                int swz1 = (lc1 * 2048 + k0 * 2) ^ ((lc1 & 7) << 4);
                acc1 = __builtin_amdgcn_mfma_f32_16x16x32_f16(ha, *(const f16x8*)(smem + swz1), acc1, 0, 0, 0);
            }
            #pragma unroll
            for (int r = 0; r < 4; ++r) {
                int row = (lane >> 4) * 4 + r;
                zred[wv * 512 + row * 32 + lcA]      = acc0[r];
                zred[wv * 512 + row * 32 + 16 + lcA] = acc1[r];
            }
            __syncthreads();
            if (tid < 128) {
                int zb = grow * 32 + gu;
                float u[4];
                #pragma unroll
                for (int q = 0; q < 4; ++q) {
                    float s = 0.f;
                    #pragma unroll
                    for (int w = 0; w < 4; ++w) s += zred[w * 512 + zb + q * 8];
                    u[q] = s;
                }
                float zi = zx[0] + u[0] + bz[0];
                float zf = zx[1] + u[1] + bz[1];
                float zo = zx[2] + u[2] + bz[2];
                float zg = zx[3] + u[3] + bz[3];
                float si = 1.f / (1.f + expf(-zi));
                float sf = 1.f / (1.f + expf(-zf));
                float so = 1.f / (1.f + expf(-zo));
                float cn = sf * creg + si * tanhf(zg);
                float hn = so * tanhf(cn);
                creg = cn;
                h0buf[(tick & 1) * 16384 + grow * 1024 + gcol] = (f16)hn;
                inp1[(tick & 3) * 16384 + grow * 1024 + gcol]  = (f16)(hn + xe);
            }
            // ---- group-0 barrier
            __syncthreads();
            if (tid == 0)
                __hip_atomic_store(&arrive[g * 16], (unsigned)(tick + 1), __ATOMIC_RELEASE, AGT);
            if (tid < GRP)
                while (__hip_atomic_load(&arrive[tid * 16], __ATOMIC_RELAXED, AGT) < (unsigned)(tick + 1)) {}
            __syncthreads();
            __threadfence();
            if (g == 0 && tid == 0)
                __hip_atomic_store(progSelf, (unsigned)(tick + 1), __ATOMIC_RELEASE, AGT);
        }
    } else {
        for (int tick = 1; tick <= 512; ++tick) {
            const int step = tick - 1;
            // wait for L0 to have completed tick-1 (inp1[step] ready)
            while (__hip_atomic_load(progOther, __ATOMIC_RELAXED, AGT) < (unsigned)tick) {}
            __threadfence();
            // LN stats of inp1[step] (f16)
            {
                int srow = tid >> 4, seg = tid & 15;
                const f16* p = inp1 + (step & 3) * 16384 + srow * 1024 + seg * 64;
                float sum = 0.f, sq = 0.f;
                #pragma unroll
                for (int j = 0; j < 8; ++j) {
                    f16x8 v = *(const f16x8*)(p + j * 8);
                    #pragma unroll
                    for (int e = 0; e < 8; ++e) { float f = (float)v[e]; sum += f; sq += f * f; }
                }
                #pragma unroll
                for (int m = 1; m < 16; m <<= 1) {
                    sum += __shfl_xor(sum, m);
                    sq  += __shfl_xor(sq,  m);
                }
                if (seg == 0) {
                    float mu  = sum * (1.f / 1024.f);
                    float var = sq * (1.f / 1024.f) - mu * mu;
                    stats[srow * 2]     = mu;
                    stats[srow * 2 + 1] = rsqrtf(var + LN_EPS);
                }
            }
            // GEMM: waves 0-1 x-half (inp1 @ Wx1'), waves 2-3 h-half (h1 @ Wh1)
            f32x4 acc0 = {0.f,0.f,0.f,0.f}, acc1 = {0.f,0.f,0.f,0.f};
            if (wv < 2) {
                const f16* xrow = inp1 + (step & 3) * 16384 + arow * 1024;
                #pragma unroll
                for (int ks = 0; ks < 16; ++ks) {
                    int k0 = wv * 512 + ks * 32 + koff;
                    f16x8 a = *(const f16x8*)(xrow + k0);
                    int swz0 = (lcA * 2048 + k0 * 2) ^ ((lcA & 7) << 4);
                    acc0 = __builtin_amdgcn_mfma_f32_16x16x32_f16(a, *(const f16x8*)(smem + swz0), acc0, 0, 0, 0);
                    int lc1 = 16 + lcA;
                    int swz1 = (lc1 * 2048 + k0 * 2) ^ ((lc1 & 7) << 4);
                    acc1 = __builtin_amdgcn_mfma_f32_16x16x32_f16(a, *(const f16x8*)(smem + swz1), acc1, 0, 0, 0);
                }
            } else {
                const f16* hrow = h1buf + (tick & 1) * 16384 + arow * 1024;  // h1[step-1]
                #pragma unroll
                for (int ks = 0; ks < 16; ++ks) {
                    int k0 = (wv - 2) * 512 + ks * 32 + koff;
                    f16x8 a = *(const f16x8*)(hrow + k0);
                    int swz0 = (lcA * 2048 + k0 * 2) ^ ((lcA & 7) << 4);
                    acc0 = __builtin_amdgcn_mfma_f32_16x16x32_f16(a, *(const f16x8*)(smem + 65536 + swz0), acc0, 0, 0, 0);
                    int lc1 = 16 + lcA;
                    int swz1 = (lc1 * 2048 + k0 * 2) ^ ((lc1 & 7) << 4);
                    acc1 = __builtin_amdgcn_mfma_f32_16x16x32_f16(a, *(const f16x8*)(smem + 65536 + swz1), acc1, 0, 0, 0);
                }
            }
            #pragma unroll
            for (int r = 0; r < 4; ++r) {
                int row = (lane >> 4) * 4 + r;
                zred[wv * 512 + row * 32 + lcA]      = acc0[r];
                zred[wv * 512 + row * 32 + 16 + lcA] = acc1[r];
            }
            __syncthreads();
            if (tid < 128) {
                int zb = grow * 32 + gu;
                float ux[4], uh[4];
                #pragma unroll
                for (int q = 0; q < 4; ++q) {
                    ux[q] = zred[zb + q * 8] + zred[512 + zb + q * 8];
                    uh[q] = zred[1024 + zb + q * 8] + zred[1536 + zb + q * 8];
                }
                float mu = stats[grow * 2], rsig = stats[grow * 2 + 1];
                float mrs = mu * rsig;
                float zi = rsig * ux[0] - mrs * Gg[0] + Cg[0] + uh[0];
                float zf = rsig * ux[1] - mrs * Gg[1] + Cg[1] + uh[1];
                float zo = rsig * ux[2] - mrs * Gg[2] + Cg[2] + uh[2];
                float zg = rsig * ux[3] - mrs * Gg[3] + Cg[3] + uh[3];
                float si = 1.f / (1.f + expf(-zi));
                float sf = 1.f / (1.f + expf(-zf));
                float so = 1.f / (1.f + expf(-zo));
                float cn = sf * creg + si * tanhf(zg);
                float hn = so * tanhf(cn);
                creg = cn;
                h1buf[(step & 1) * 16384 + grow * 1024 + gcol] = (f16)hn;
                hseq[(size_t)(step * 16 + grow) * 1024 + gcol] = (f16)hn;
            }
            // ---- group-1 barrier
            __syncthreads();
            if (tid == 0)
                __hip_atomic_store(&arrive[g * 16], (unsigned)tick, __ATOMIC_RELEASE, AGT);
            if (tid < GRP)
                while (__hip_atomic_load(&arrive[tid * 16], __ATOMIC_RELAXED, AGT) < (unsigned)tick) {}
            __syncthreads();
            __threadfence();
            if (g == 0 && tid == 0)
                __hip_atomic_store(progSelf, (unsigned)tick, __ATOMIC_RELEASE, AGT);
        }
    }

    if (tid < 128)
        cout[layer * 16384 + grow * 1024 + gcol] = creg;
}

// ---------------------------------------------------------------------------
// logits = hseq(f16 [8192][1024]) @ embed_f16([32000][1024])^T -> fp32 'bsv'
__global__ void __launch_bounds__(256)
k_logits(const f16* __restrict__ A, const f16* __restrict__ Bm, float* __restrict__ out) {
    __shared__ f16 Asm[128 * 64];
    __shared__ f16 Bsm[128 * 64];
    const int nwg = gridDim.x;                       // 16000, %8==0
    int swz = (blockIdx.x % 8) * (nwg / 8) + blockIdx.x / 8;
    const int tm = swz / 250;
    const int tn = swz % 250;
    const int tid = threadIdx.x;
    const int lane = tid & 63;
    const int wv = tid >> 6;
    const int wm = wv >> 1, wn = wv & 1;

    f32x4 acc[4][4] = {};
    const f16* Ab = A  + (size_t)(tm * 128) * 1024;
    const f16* Bb = Bm + (size_t)(tn * 128) * 1024;

    for (int kt = 0; kt < 16; ++kt) {
        uint4 ra[4], rb[4];
        #pragma unroll
        for (int j = 0; j < 4; ++j) {
            int c = tid + j * 256;
            int row = c >> 3, slot = c & 7;
            ra[j] = *(const uint4*)(Ab + (size_t)row * 1024 + kt * 64 + slot * 8);
            rb[j] = *(const uint4*)(Bb + (size_t)row * 1024 + kt * 64 + slot * 8);
        }
        __syncthreads();
        #pragma unroll
        for (int j = 0; j < 4; ++j) {
            int c = tid + j * 256;
            int row = c >> 3, slot = c & 7;
            int off = row * 128 + ((slot ^ (row & 7)) << 4);
            *(uint4*)((char*)Asm + off) = ra[j];
            *(uint4*)((char*)Bsm + off) = rb[j];
        }
        __syncthreads();
        #pragma unroll
        for (int ks = 0; ks < 2; ++ks) {
            f16x8 af[4], bf[4];
            #pragma unroll
            for (int mi = 0; mi < 4; ++mi) {
                int row = wm * 64 + mi * 16 + (lane & 15);
                int slot = ks * 4 + (lane >> 4);
                af[mi] = *(const f16x8*)((const char*)Asm + row * 128 + ((slot ^ (row & 7)) << 4));
            }
            #pragma unroll
            for (int ni = 0; ni < 4; ++ni) {
                int row = wn * 64 + ni * 16 + (lane & 15);
                int slot = ks * 4 + (lane >> 4);
                bf[ni] = *(const f16x8*)((const char*)Bsm + row * 128 + ((slot ^ (row & 7)) << 4));
            }
            #pragma unroll
            for (int mi = 0; mi < 4; ++mi)
                #pragma unroll
                for (int ni = 0; ni < 4; ++ni)
                    acc[mi][ni] = __builtin_amdgcn_mfma_f32_16x16x32_f16(af[mi], bf[ni], acc[mi][ni], 0, 0, 0);
        }
    }
    #pragma unroll
    for (int mi = 0; mi < 4; ++mi) {
        int m16 = tm * 128 + wm * 64 + mi * 16;
        int s = m16 >> 4;
        #pragma unroll
        for (int ni = 0; ni < 4; ++ni) {
            int v = tn * 128 + wn * 64 + ni * 16 + (lane & 15);
            #pragma unroll
            for (int r = 0; r < 4; ++r) {
                int b = (lane >> 4) * 4 + r;
                out[((size_t)b * 512 + s) * 32000 + v] = acc[mi][ni][r];
            }
        }
    }
}

// ---------------------------------------------------------------------------
extern "C" void kernel_launch(void* const* d_in, const int* in_sizes, int n_in,
                              void* d_out, int out_size, void* d_ws, size_t ws_size,
                              hipStream_t stream) {
    const int*   x     = (const int*)d_in[0];
    const float* embed = (const float*)d_in[1];
    const float* gamma = (const float*)d_in[2];
    const float* beta  = (const float*)d_in[3];
    const float* W     = (const float*)d_in[4];
    const float* bias  = (const float*)d_in[5];
    float* out = (float*)d_out;

    char* p = (char*)d_ws;
    size_t off = 0;
    f16*      hseq  = (f16*)(p + off);      off += 16777216;   // [8192][1024] f16
    float2*   xstat = (float2*)(p + off);   off += 65536;
    f16*      h0buf = (f16*)(p + off);      off += 65536;      // [2][16][1024]
    f16*      h1buf = (f16*)(p + off);      off += 65536;
    f16*      inp1  = (f16*)(p + off);      off += 131072;     // [4][16][1024]
    unsigned* flags = (unsigned*)(p + off); off += 16896;
    size_t xn0_off = off;
    f16*      xn0   = (f16*)(p + off);      off += 16777216;
    f16*      WxT0  = (f16*)(p + off);      off += 8388608;
    f16*      WhT0  = (f16*)(p + off);      off += 8388608;
    f16*      WxT1  = (f16*)(p + off);      off += 8388608;
    f16*      WhT1  = (f16*)(p + off);      off += 8388608;
    float*    G1    = (float*)(p + off);    off += 16384;
    float*    Bv1   = (float*)(p + off);    off += 16384;
    f16*      zx0   = (f16*)(p + off);      off += 67108864;   // [8192][4096] f16
    f16*      embed_f16 = (f16*)(p + xn0_off);   // aliases xn0..zx0 (dead after k_recur)

    // --- recurrence-independent prep
    k_xstat<<<2048, 256, 0, stream>>>(x, embed, xstat);
    k_xnorm<<<8192, 256, 0, stream>>>(x, embed, xstat, gamma, beta, xn0);
    k_wprep<<<4096, 256, 0, stream>>>(W, gamma, WxT0, WhT0, WxT1, WhT1);
    k_gb<<<16, 256, 0, stream>>>(W, gamma, beta, G1, Bv1);
    k_zx<<<2048, 256, 0, stream>>>(xn0, WxT0, zx0);

    hipMemsetAsync(h0buf, 0, 131072, stream);   // h0 + h1 (adjacent)
    hipMemsetAsync(flags, 0, 16896, stream);

    // --- persistent recurrence
    hipFuncSetAttribute((const void*)k_recur,
                        hipFuncAttributeMaxDynamicSharedMemorySize, 139392);
    void* ka[] = { (void*)&x, (void*)&embed, (void*)&bias, (void*)&zx0,
                   (void*)&WhT0, (void*)&WxT1, (void*)&WhT1,
                   (void*)&G1, (void*)&Bv1,
                   (void*)&h0buf, (void*)&h1buf, (void*)&inp1,
                   (void*)&hseq, (void*)&flags, (void*)&out };
    hipLaunchCooperativeKernel((const void*)k_recur, dim3(256), dim3(256),
                               ka, 139392, stream);

    // --- logits (embed_f16 reuses prep space, safe after k_recur)
    k_cvt<<<2048, 256, 0, stream>>>(embed, embed_f16, 32000 * 1024 / 4);
    k_logits<<<16000, 256, 0, stream>>>(hseq, embed_f16, out + 32768);
}